// Round 14
// baseline (395.042 us; speedup 1.0000x reference)
//
#include <hip/hip_runtime.h>
#include <math.h>

#define D_IN 128
typedef unsigned short ushort_t;
typedef __attribute__((ext_vector_type(8))) short short8;
typedef __attribute__((ext_vector_type(4))) float f32x4;

__device__ __forceinline__ float bf2f(ushort_t u) {
    union { unsigned i; float f; } x;
    x.i = ((unsigned)u) << 16;
    return x.f;
}
__device__ __forceinline__ ushort_t f2bf(float f) {
    unsigned i = __float_as_uint(f);
    unsigned r = (i + 0x7fffu + ((i >> 16) & 1u)) >> 16;
    return (ushort_t)r;
}

// ---------------- single-pass dual binning (packed staging) ----------------
// CH=256-node chunks, 1024-thread blocks.
// Staging A (dst-binned): int2 { src | dlocal<<17, w_bits_fp32 }
// Staging B (src-binned): uint { slocal<<16 | bf16(w) }   (R14: halved)
#define CH 256
#define CHS 8
#define CAP 6144
#define MAXCH 512
#define NBIN 256

__global__ __launch_bounds__(1024) void bin2_kernel(const int* __restrict__ src,
                                                    const int* __restrict__ dst,
                                                    const float* __restrict__ w,
                                                    int* __restrict__ gcA, int* __restrict__ gcB,
                                                    int2* __restrict__ stA,
                                                    unsigned* __restrict__ stB, int E, int nch) {
    __shared__ int cntA[MAXCH], baseA[MAXCH], posA[MAXCH];
    __shared__ int cntB[MAXCH], baseB[MAXCH], posB[MAXCH];
    const int NT = 1024;
    for (int i = threadIdx.x; i < nch; i += NT) {
        cntA[i] = 0; posA[i] = 0; cntB[i] = 0; posB[i] = 0;
    }
    __syncthreads();
    int per = (E + gridDim.x - 1) / gridDim.x;
    int e0 = blockIdx.x * per, e1 = min(E, e0 + per);
    for (int e = e0 + threadIdx.x; e < e1; e += NT) {
        atomicAdd(&cntA[dst[e] >> CHS], 1);
        atomicAdd(&cntB[src[e] >> CHS], 1);
    }
    __syncthreads();
    for (int i = threadIdx.x; i < nch; i += NT) {
        int c = cntA[i];
        baseA[i] = c ? atomicAdd(&gcA[i], c) : 0;
        c = cntB[i];
        baseB[i] = c ? atomicAdd(&gcB[i], c) : 0;
    }
    __syncthreads();
    for (int e = e0 + threadIdx.x; e < e1; e += NT) {
        int s = src[e], d = dst[e];
        float wf = w[e];
        int cA = d >> CHS;
        int pA = baseA[cA] + atomicAdd(&posA[cA], 1);
        if (pA < CAP) {
            int2 o;
            o.x = s | ((d & (CH - 1)) << 17);
            o.y = __float_as_int(wf);
            stA[(size_t)cA * CAP + pA] = o;
        }
        int cB = s >> CHS;
        int pB = baseB[cB] + atomicAdd(&posB[cB], 1);
        if (pB < CAP) {
            stB[(size_t)cB * CAP + pB] =
                ((unsigned)(s & (CH - 1)) << 16) | (unsigned)f2bf(wf);
        }
    }
}

// ---------------- per-chunk deg segment-sum (packed stB) ----------------
__global__ __launch_bounds__(256) void deg_chunk_kernel(const int* __restrict__ gcB,
                                                        const unsigned* __restrict__ stB,
                                                        float* __restrict__ deg, int n) {
    __shared__ float acc[CH];
    int c = blockIdx.x, kb = blockIdx.y, KB = gridDim.y;
    for (int i = threadIdx.x; i < CH; i += 256) acc[i] = 0.f;
    __syncthreads();
    int m = min(gcB[c], CAP);
    int per = (m + KB - 1) / KB;
    int i0 = kb * per, i1 = min(m, i0 + per);
    size_t base = (size_t)c * CAP;
    for (int i = i0 + threadIdx.x; i < i1; i += 256) {
        unsigned v = stB[base + i];
        atomicAdd(&acc[v >> 16], bf2f((ushort_t)(v & 0xFFFFu)));
    }
    __syncthreads();
    int nb = c * CH, lim = min(CH, n - nb);
    for (int i = threadIdx.x; i < lim; i += 256) {
        float v = acc[i];
        if (v != 0.f) atomicAdd(&deg[nb + i], v);
    }
}

__global__ void dinv_kernel(float* __restrict__ deg, int n) {
    int i = blockIdx.x * blockDim.x + threadIdx.x;
    if (i >= n) return;
    float d = deg[i];
    deg[i] = (d > 0.f) ? rsqrtf(d) : 0.f;
}

// ---------------- chunk-base scan (1 block, 512 threads, nch <= 512) ----------------
__global__ __launch_bounds__(512) void cbase_kernel(const int* __restrict__ gcA,
                                                    int* __restrict__ cbase,
                                                    int* __restrict__ rp, int nch, int n) {
    __shared__ int sd[MAXCH];
    int t = threadIdx.x;
    sd[t] = (t < nch) ? min(gcA[t], CAP) : 0;
    __syncthreads();
    for (int off = 1; off < MAXCH; off <<= 1) {
        int y = (t >= off) ? sd[t - off] : 0;
        __syncthreads();
        sd[t] += y;
        __syncthreads();
    }
    if (t < nch) cbase[t] = (t > 0) ? sd[t - 1] : 0;
    if (t == 0) rp[n] = sd[nch - 1];
}

// ---------------- per-chunk CSR build: count -> scan -> rp -> octile-ordered scatter ----------------
// R14: scatter in 8 passes by src-octile (src>>14) so each row's edge list is
// src-sorted at 16K granularity -> spmm's concurrent gathers cluster in ~2-4MB
// windows -> L2-resident.
__global__ __launch_bounds__(256) void csr_chunk_kernel(const int* __restrict__ gcA,
                                                        const int* __restrict__ cbase,
                                                        const int2* __restrict__ stA,
                                                        const float* __restrict__ dinv,
                                                        int* __restrict__ rp,
                                                        int2* __restrict__ cv, int n) {
    __shared__ int lcnt[CH];
    __shared__ int lrp[CH];
    __shared__ float ldinv[CH];
    __shared__ int sdata[256];
    int c = blockIdx.x;
    int nb = c * CH, lim = min(CH, n - nb);
    int m = min(gcA[c], CAP);
    size_t sb = (size_t)c * CAP;
    int t = threadIdx.x;
    if (t < CH) lcnt[t] = 0;
    if (t < lim) ldinv[t] = dinv[nb + t];
    __syncthreads();
    for (int i = t; i < m; i += 256) atomicAdd(&lcnt[stA[sb + i].x >> 17], 1);
    __syncthreads();
    int v = (t < CH) ? lcnt[t] : 0;
    sdata[t] = v;
    __syncthreads();
    for (int off = 1; off < 256; off <<= 1) {
        int y = (t >= off) ? sdata[t - off] : 0;
        __syncthreads();
        sdata[t] += y;
        __syncthreads();
    }
    if (t < CH) lrp[t] = sdata[t] - v;
    __syncthreads();
    int base = cbase[c];
    if (t < lim) rp[nb + t] = base + lrp[t];
    if (t < CH) lcnt[t] = 0;
    __syncthreads();
    // octile-filtered scatter passes (src 17 bits -> (src>>14) in [0,7])
    for (int oc = 0; oc < 8; ++oc) {
        for (int i = t; i < m; i += 256) {
            int2 sv = stA[sb + i];
            int sN = sv.x & 0x1FFFF;
            if ((sN >> 14) != oc) continue;
            int dl = sv.x >> 17;
            float nv = dinv[sN] * __int_as_float(sv.y) * ldinv[dl];
            int o = base + lrp[dl] + atomicAdd(&lcnt[dl], 1);
            int2 oo;
            oo.x = sN;
            oo.y = __float_as_int(nv);
            cv[o] = oo;
        }
        __syncthreads();
    }
}

// ---------------- merged W transpose + bf16 for all 3 layers ----------------
__global__ void wt_all_kernel(const float* __restrict__ W1, const float* __restrict__ W2,
                              const float* __restrict__ W3, ushort_t* __restrict__ Wt1,
                              ushort_t* __restrict__ Wt2, ushort_t* __restrict__ Wt3) {
    int i = blockIdx.x * blockDim.x + threadIdx.x;
    if (i < 24576) {
        int m = i / 8192, rem = i % 8192, f = rem / 64, g = rem % 64;
        Wt1[((size_t)(m * 64 + g)) * 128 + f] = f2bf(W1[i]);
    } else if (i < 24576 + 6144) {
        int j = i - 24576;
        int m = j / 2048, rem = j % 2048, f = rem / 32, g = rem % 32;
        Wt2[((size_t)(m * 32 + g)) * 64 + f] = f2bf(W2[j]);
    } else if (i < 24576 + 6144 + 1536) {
        int j = i - 24576 - 6144;
        int m = j / 512, rem = j % 512, f = rem / 16, g = rem % 16;
        Wt3[((size_t)(m * 16 + g)) * 32 + f] = f2bf(W3[j]);
    }
}

// ---------------- MFMA GEMM: 32 rows/wave (two A-frags share each B-frag) ----------------
template <int F, int G, bool A_BF16>
__global__ __launch_bounds__(256) void gemm_mfma(const void* __restrict__ Hv,
                                                 const ushort_t* __restrict__ Wt,
                                                 ushort_t* __restrict__ YA16,
                                                 ushort_t* __restrict__ YB16,
                                                 ushort_t* __restrict__ C16, int n) {
    constexpr int CT = G / 16;
    const int tid = threadIdx.x;
    const int wave = tid >> 6;
    const int lane = tid & 63;
    const int l16 = lane & 15;
    const int lk8 = (lane >> 4) * 8;

    const int rowBase = blockIdx.x * 128 + wave * 32;
    int rA0 = rowBase + l16;
    int rA1 = rowBase + 16 + l16;
    if (rA0 >= n) rA0 = n - 1;
    if (rA1 >= n) rA1 = n - 1;

    f32x4 acc[2][3][CT];
#pragma unroll
    for (int h = 0; h < 2; ++h)
#pragma unroll
        for (int m = 0; m < 3; ++m)
#pragma unroll
            for (int ct = 0; ct < CT; ++ct)
#pragma unroll
                for (int j = 0; j < 4; ++j) acc[h][m][ct][j] = 0.f;

#pragma unroll
    for (int ks = 0; ks < F; ks += 32) {
        short8 a0, a1;
        if constexpr (A_BF16) {
            a0 = *(const short8*)((const ushort_t*)Hv + (size_t)rA0 * F + ks + lk8);
            a1 = *(const short8*)((const ushort_t*)Hv + (size_t)rA1 * F + ks + lk8);
        } else {
            const float* ap0 = (const float*)Hv + (size_t)rA0 * F + ks + lk8;
            const float* ap1 = (const float*)Hv + (size_t)rA1 * F + ks + lk8;
            float4 f00 = *(const float4*)ap0;
            float4 f01 = *(const float4*)(ap0 + 4);
            float4 f10 = *(const float4*)ap1;
            float4 f11 = *(const float4*)(ap1 + 4);
            a0[0] = (short)f2bf(f00.x); a0[1] = (short)f2bf(f00.y);
            a0[2] = (short)f2bf(f00.z); a0[3] = (short)f2bf(f00.w);
            a0[4] = (short)f2bf(f01.x); a0[5] = (short)f2bf(f01.y);
            a0[6] = (short)f2bf(f01.z); a0[7] = (short)f2bf(f01.w);
            a1[0] = (short)f2bf(f10.x); a1[1] = (short)f2bf(f10.y);
            a1[2] = (short)f2bf(f10.z); a1[3] = (short)f2bf(f10.w);
            a1[4] = (short)f2bf(f11.x); a1[5] = (short)f2bf(f11.y);
            a1[6] = (short)f2bf(f11.z); a1[7] = (short)f2bf(f11.w);
        }
#pragma unroll
        for (int m = 0; m < 3; ++m) {
#pragma unroll
            for (int ct = 0; ct < CT; ++ct) {
                short8 b = *(const short8*)(Wt + ((size_t)(m * G + ct * 16 + l16)) * F +
                                            ks + lk8);
                acc[0][m][ct] = __builtin_amdgcn_mfma_f32_16x16x32_bf16(a0, b, acc[0][m][ct], 0, 0, 0);
                acc[1][m][ct] = __builtin_amdgcn_mfma_f32_16x16x32_bf16(a1, b, acc[1][m][ct], 0, 0, 0);
            }
        }
    }

#pragma unroll
    for (int h = 0; h < 2; ++h) {
        const int r0 = rowBase + h * 16 + (lane >> 4) * 4;
#pragma unroll
        for (int ct = 0; ct < CT; ++ct) {
            const int col = ct * 16 + l16;
#pragma unroll
            for (int j = 0; j < 4; ++j) {
                int r = r0 + j;
                if (r < n) {
                    size_t idx = (size_t)r * G + col;
                    YA16[idx] = f2bf(acc[h][0][ct][j] - acc[h][2][ct][j]);
                    YB16[idx] = f2bf(acc[h][1][ct][j]);
                    C16[idx] = f2bf(acc[h][2][ct][j]);
                }
            }
        }
    }
}

// ---------------- row-major bf16 SpMM, 8-deep gather pipeline ----------------
template <int G, int MODE>
__global__ __launch_bounds__(256) void spmm_bf16(const ushort_t* __restrict__ Hg,
                                                 const ushort_t* __restrict__ Yres,
                                                 const float* __restrict__ bias,
                                                 ushort_t* __restrict__ outS,
                                                 const int2* __restrict__ cv,
                                                 const int* __restrict__ rp, int n) {
    constexpr int TPR = G / 4;
    constexpr int RPB = 256 / TPR;
    int row = blockIdx.x * RPB + threadIdx.x / TPR;
    if (row >= n) return;
    int g = (threadIdx.x % TPR) * 4;
    float a0 = 0.f, a1 = 0.f, a2 = 0.f, a3 = 0.f;
    int e = rp[row], e1 = rp[row + 1];
    for (; e + 8 <= e1; e += 8) {
        int2 c[8];
        ushort4 h[8];
#pragma unroll
        for (int k = 0; k < 8; ++k) c[k] = cv[e + k];
#pragma unroll
        for (int k = 0; k < 8; ++k) h[k] = *(const ushort4*)(Hg + (size_t)c[k].x * G + g);
#pragma unroll
        for (int k = 0; k < 8; ++k) {
            float v = __int_as_float(c[k].y);
            a0 = fmaf(v, bf2f(h[k].x), a0);
            a1 = fmaf(v, bf2f(h[k].y), a1);
            a2 = fmaf(v, bf2f(h[k].z), a2);
            a3 = fmaf(v, bf2f(h[k].w), a3);
        }
    }
    for (; e + 4 <= e1; e += 4) {
        int2 c[4];
        ushort4 h[4];
#pragma unroll
        for (int k = 0; k < 4; ++k) c[k] = cv[e + k];
#pragma unroll
        for (int k = 0; k < 4; ++k) h[k] = *(const ushort4*)(Hg + (size_t)c[k].x * G + g);
#pragma unroll
        for (int k = 0; k < 4; ++k) {
            float v = __int_as_float(c[k].y);
            a0 = fmaf(v, bf2f(h[k].x), a0);
            a1 = fmaf(v, bf2f(h[k].y), a1);
            a2 = fmaf(v, bf2f(h[k].z), a2);
            a3 = fmaf(v, bf2f(h[k].w), a3);
        }
    }
    for (; e < e1; ++e) {
        int2 c = cv[e];
        float v = __int_as_float(c.y);
        ushort4 hv = *(const ushort4*)(Hg + (size_t)c.x * G + g);
        a0 = fmaf(v, bf2f(hv.x), a0);
        a1 = fmaf(v, bf2f(hv.y), a1);
        a2 = fmaf(v, bf2f(hv.z), a2);
        a3 = fmaf(v, bf2f(hv.w), a3);
    }
    size_t idx = (size_t)row * G + g;
    ushort4 yv = *(const ushort4*)(Yres + idx);
    ushort4 o;
    if (MODE == 1) {
        o.x = f2bf(bf2f(yv.x) - 2.f * a0);
        o.y = f2bf(bf2f(yv.y) - 2.f * a1);
        o.z = f2bf(bf2f(yv.z) - 2.f * a2);
        o.w = f2bf(bf2f(yv.w) - 2.f * a3);
    } else {
        float4 bv = *(const float4*)(bias + g);
        o.x = f2bf(fmaxf(bf2f(yv.x) - a0 + bv.x, 0.f));
        o.y = f2bf(fmaxf(bf2f(yv.y) - a1 + bv.y, 0.f));
        o.z = f2bf(fmaxf(bf2f(yv.z) - a2 + bv.z, 0.f));
        o.w = f2bf(fmaxf(bf2f(yv.w) - a3 + bv.w, 0.f));
    }
    *(ushort4*)(outS + idx) = o;
}

// ---------------- layer 4 (fp32 tables; bf16 H3 input) ----------------

__global__ void gemm4(const ushort_t* __restrict__ H, const float* __restrict__ W,
                      float* __restrict__ YA, float* __restrict__ YB, float* __restrict__ C,
                      int n) {
    __shared__ float Ws[3 * 16 * 4];
    if (threadIdx.x < 192) Ws[threadIdx.x] = W[threadIdx.x];
    __syncthreads();
    int i = blockIdx.x * blockDim.x + threadIdx.x;
    if (i >= n) return;
    const ushort_t* h = H + (size_t)i * 16;
    float a[4], b[4], c[4];
#pragma unroll
    for (int g = 0; g < 4; ++g) a[g] = b[g] = c[g] = 0.f;
#pragma unroll
    for (int j = 0; j < 2; ++j) {
        short8 hv = *(const short8*)(h + j * 8);
#pragma unroll
        for (int k = 0; k < 8; ++k) {
            int f = j * 8 + k;
            float hf = bf2f((ushort_t)hv[k]);
#pragma unroll
            for (int g = 0; g < 4; ++g) {
                a[g] = fmaf(hf, Ws[f * 4 + g], a[g]);
                b[g] = fmaf(hf, Ws[64 + f * 4 + g], b[g]);
                c[g] = fmaf(hf, Ws[128 + f * 4 + g], c[g]);
            }
        }
    }
    float4 oa, ob, oc;
    oa.x = a[0] - c[0]; oa.y = a[1] - c[1]; oa.z = a[2] - c[2]; oa.w = a[3] - c[3];
    ob.x = b[0]; ob.y = b[1]; ob.z = b[2]; ob.w = b[3];
    oc.x = c[0]; oc.y = c[1]; oc.z = c[2]; oc.w = c[3];
    *(float4*)(YA + (size_t)i * 4) = oa;
    *(float4*)(YB + (size_t)i * 4) = ob;
    *(float4*)(C + (size_t)i * 4) = oc;
}

__global__ void spmm4(const float* __restrict__ C, const float* __restrict__ YB,
                      float* __restrict__ S, const int2* __restrict__ cv,
                      const int* __restrict__ rp, int n) {
    int row = blockIdx.x * blockDim.x + threadIdx.x;
    if (row >= n) return;
    float a0 = 0.f, a1 = 0.f, a2 = 0.f, a3 = 0.f;
    int e1 = rp[row + 1];
    for (int e = rp[row]; e < e1; ++e) {
        int2 c = cv[e];
        float v = __int_as_float(c.y);
        float4 cvv = *(const float4*)(C + (size_t)c.x * 4);
        a0 = fmaf(v, cvv.x, a0);
        a1 = fmaf(v, cvv.y, a1);
        a2 = fmaf(v, cvv.z, a2);
        a3 = fmaf(v, cvv.w, a3);
    }
    float4 yb = *(const float4*)(YB + (size_t)row * 4);
    float4 o;
    o.x = yb.x - 2.f * a0;
    o.y = yb.y - 2.f * a1;
    o.z = yb.z - 2.f * a2;
    o.w = yb.w - 2.f * a3;
    *(float4*)(S + (size_t)row * 4) = o;
}

__global__ void layer4_final(const float* __restrict__ S, const float* __restrict__ YA,
                             const float* __restrict__ b, float* __restrict__ out,
                             const int2* __restrict__ cv, const int* __restrict__ rp, int n) {
    int row = blockIdx.x * blockDim.x + threadIdx.x;
    if (row >= n) return;
    float a0 = 0.f, a1 = 0.f, a2 = 0.f, a3 = 0.f;
    int e1 = rp[row + 1];
    for (int e = rp[row]; e < e1; ++e) {
        int2 c = cv[e];
        float v = __int_as_float(c.y);
        float4 sv = *(const float4*)(S + (size_t)c.x * 4);
        a0 = fmaf(v, sv.x, a0);
        a1 = fmaf(v, sv.y, a1);
        a2 = fmaf(v, sv.z, a2);
        a3 = fmaf(v, sv.w, a3);
    }
    float4 ya = *(const float4*)(YA + (size_t)row * 4);
    float o0 = ya.x - a0 + b[0];
    float o1 = ya.y - a1 + b[1];
    float o2 = ya.z - a2 + b[2];
    float o3 = ya.w - a3 + b[3];
    float m = fmaxf(fmaxf(o0, o1), fmaxf(o2, o3));
    float s = expf(o0 - m) + expf(o1 - m) + expf(o2 - m) + expf(o3 - m);
    float ls = m + logf(s);
    float4 r;
    r.x = o0 - ls;
    r.y = o1 - ls;
    r.z = o2 - ls;
    r.w = o3 - ls;
    *(float4*)(out + (size_t)row * 4) = r;
}

// ---------------- launch ----------------

static inline char* align_up(char* p, size_t a) {
    return (char*)(((uintptr_t)p + a - 1) & ~(uintptr_t)(a - 1));
}

extern "C" void kernel_launch(void* const* d_in, const int* in_sizes, int n_in,
                              void* d_out, int out_size, void* d_ws, size_t ws_size,
                              hipStream_t stream) {
    const float* x = (const float*)d_in[0];
    const int* ei = (const int*)d_in[1];
    const float* ew = (const float*)d_in[2];
    const float* W1 = (const float*)d_in[3];
    const float* b1 = (const float*)d_in[4];
    const float* W2 = (const float*)d_in[5];
    const float* b2 = (const float*)d_in[6];
    const float* W3 = (const float*)d_in[7];
    const float* b3 = (const float*)d_in[8];
    const float* W4 = (const float*)d_in[9];
    const float* b4 = (const float*)d_in[10];
    float* out = (float*)d_out;

    const int n = in_sizes[0] / D_IN;  // 100000
    const int E = in_sizes[2];         // 1600000
    const int* src = ei;
    const int* dst = ei + E;
    const int nch = (n + CH - 1) / CH;  // 391

    char* p = (char*)d_ws;
    int2* cv = (int2*)p;          p += (size_t)E * 8;
    float* deg = (float*)p;       p += (size_t)n * 4;
    int* rp = (int*)p;            p = align_up(p + (size_t)(n + 1) * 4, 64);
    int* gcA = (int*)p;           p += MAXCH * 4;
    int* gcB = (int*)p;           p += MAXCH * 4;
    int* cbase = (int*)p;         p = align_up(p + MAXCH * 4, 64);
    ushort_t* Wt1 = (ushort_t*)p; p = align_up(p + (size_t)192 * 128 * 2, 64);
    ushort_t* Wt2 = (ushort_t*)p; p = align_up(p + (size_t)96 * 64 * 2, 64);
    ushort_t* Wt3 = (ushort_t*)p; p = align_up(p + (size_t)48 * 32 * 2, 64);
    // big region: staging (dead after CSR build) overlaid with YA16/YB16/C16/S16
    char* big = p;
    ushort_t* YA16 = (ushort_t*)big;
    ushort_t* YB16 = (ushort_t*)(big + (size_t)n * 64 * 2);
    ushort_t* C16 = (ushort_t*)(big + (size_t)n * 64 * 2 * 2);
    ushort_t* S16 = (ushort_t*)(big + (size_t)n * 64 * 2 * 3);
    int2* stA = (int2*)big;                                    // nch*CAP*8 = 19.2MB
    unsigned* stB = (unsigned*)(big + (size_t)nch * CAP * 8);  // nch*CAP*4 = 9.6MB
    p = align_up(big + (size_t)n * 64 * 2 * 4, 64);
    ushort_t* H1 = (ushort_t*)p;  p = align_up(p + (size_t)n * 64 * 2, 64);
    ushort_t* H2 = (ushort_t*)p;  p = align_up(p + (size_t)n * 32 * 2, 64);
    ushort_t* H3 = (ushort_t*)p;  p = align_up(p + (size_t)n * 16 * 2, 64);
    float* YA4 = (float*)p;       p = align_up(p + (size_t)n * 4 * 4, 64);
    float* YB4 = (float*)p;       p = align_up(p + (size_t)n * 4 * 4, 64);
    float* C4 = (float*)p;        p = align_up(p + (size_t)n * 4 * 4, 64);
    float* S4 = (float*)p;        p = align_up(p + (size_t)n * 4 * 4, 64);

    const int TB = 256;
    int nb256 = (n + TB - 1) / TB;
    int gm = (n + 127) / 128;

    // ---- preprocessing ----
    hipMemsetAsync(deg, 0, (size_t)n * 4, stream);
    hipMemsetAsync(gcA, 0, MAXCH * 4 * 2, stream);
    bin2_kernel<<<NBIN, 1024, 0, stream>>>(src, dst, ew, gcA, gcB, stA, stB, E, nch);
    {
        dim3 dg(nch, 4);
        deg_chunk_kernel<<<dg, 256, 0, stream>>>(gcB, stB, deg, n);
    }
    dinv_kernel<<<nb256, TB, 0, stream>>>(deg, n);
    cbase_kernel<<<1, MAXCH, 0, stream>>>(gcA, cbase, rp, nch, n);
    csr_chunk_kernel<<<nch, 256, 0, stream>>>(gcA, cbase, stA, deg, rp, cv, n);

    wt_all_kernel<<<(24576 + 6144 + 1536 + 255) / 256, 256, 0, stream>>>(W1, W2, W3, Wt1,
                                                                         Wt2, Wt3);

    // ---- layer 1: F=128, G=64 ----
    {
        constexpr int G = 64;
        gemm_mfma<128, G, false><<<gm, 256, 0, stream>>>(x, Wt1, YA16, YB16, C16, n);
        int sb = (n + (1024 / G) - 1) / (1024 / G);
        spmm_bf16<G, 1><<<sb, 256, 0, stream>>>(C16, YB16, nullptr, S16, cv, rp, n);
        spmm_bf16<G, 2><<<sb, 256, 0, stream>>>(S16, YA16, b1, H1, cv, rp, n);
    }
    // ---- layer 2: F=64, G=32 ----
    {
        constexpr int G = 32;
        gemm_mfma<64, G, true><<<gm, 256, 0, stream>>>(H1, Wt2, YA16, YB16, C16, n);
        int sb = (n + (1024 / G) - 1) / (1024 / G);
        spmm_bf16<G, 1><<<sb, 256, 0, stream>>>(C16, YB16, nullptr, S16, cv, rp, n);
        spmm_bf16<G, 2><<<sb, 256, 0, stream>>>(S16, YA16, b2, H2, cv, rp, n);
    }
    // ---- layer 3: F=32, G=16 ----
    {
        constexpr int G = 16;
        gemm_mfma<32, G, true><<<gm, 256, 0, stream>>>(H2, Wt3, YA16, YB16, C16, n);
        int sb = (n + (1024 / G) - 1) / (1024 / G);
        spmm_bf16<G, 1><<<sb, 256, 0, stream>>>(C16, YB16, nullptr, S16, cv, rp, n);
        spmm_bf16<G, 2><<<sb, 256, 0, stream>>>(S16, YA16, b3, H3, cv, rp, n);
    }
    // ---- layer 4: F=16, G=4 (fp32 tables) ----
    {
        gemm4<<<nb256, 256, 0, stream>>>(H3, W4, YA4, YB4, C4, n);
        spmm4<<<nb256, 256, 0, stream>>>(C4, YB4, S4, cv, rp, n);
        layer4_final<<<nb256, 256, 0, stream>>>(S4, YA4, b4, out, cv, rp, n);
    }
}

// Round 15
// 367.051 us; speedup vs baseline: 1.0763x; 1.0763x over previous
//
#include <hip/hip_runtime.h>
#include <math.h>

#define D_IN 128
typedef unsigned short ushort_t;
typedef __attribute__((ext_vector_type(8))) short short8;
typedef __attribute__((ext_vector_type(4))) float f32x4;

__device__ __forceinline__ float bf2f(ushort_t u) {
    union { unsigned i; float f; } x;
    x.i = ((unsigned)u) << 16;
    return x.f;
}
__device__ __forceinline__ ushort_t f2bf(float f) {
    unsigned i = __float_as_uint(f);
    unsigned r = (i + 0x7fffu + ((i >> 16) & 1u)) >> 16;
    return (ushort_t)r;
}

// ---------------- single-pass dual binning (packed staging) ----------------
// CH=256-node chunks, 1024-thread blocks.
// Staging A (dst-binned): int2 { src | dlocal<<17, w_bits_fp32 }
// Staging B (src-binned): uint { slocal<<16 | bf16(w) }
#define CH 256
#define CHS 8
#define CAP 6144
#define MAXCH 512
#define NBIN 256

__global__ __launch_bounds__(1024) void bin2_kernel(const int* __restrict__ src,
                                                    const int* __restrict__ dst,
                                                    const float* __restrict__ w,
                                                    int* __restrict__ gcA, int* __restrict__ gcB,
                                                    int2* __restrict__ stA,
                                                    unsigned* __restrict__ stB, int E, int nch) {
    __shared__ int cntA[MAXCH], baseA[MAXCH], posA[MAXCH];
    __shared__ int cntB[MAXCH], baseB[MAXCH], posB[MAXCH];
    const int NT = 1024;
    for (int i = threadIdx.x; i < nch; i += NT) {
        cntA[i] = 0; posA[i] = 0; cntB[i] = 0; posB[i] = 0;
    }
    __syncthreads();
    int per = (E + gridDim.x - 1) / gridDim.x;
    int e0 = blockIdx.x * per, e1 = min(E, e0 + per);
    for (int e = e0 + threadIdx.x; e < e1; e += NT) {
        atomicAdd(&cntA[dst[e] >> CHS], 1);
        atomicAdd(&cntB[src[e] >> CHS], 1);
    }
    __syncthreads();
    for (int i = threadIdx.x; i < nch; i += NT) {
        int c = cntA[i];
        baseA[i] = c ? atomicAdd(&gcA[i], c) : 0;
        c = cntB[i];
        baseB[i] = c ? atomicAdd(&gcB[i], c) : 0;
    }
    __syncthreads();
    for (int e = e0 + threadIdx.x; e < e1; e += NT) {
        int s = src[e], d = dst[e];
        float wf = w[e];
        int cA = d >> CHS;
        int pA = baseA[cA] + atomicAdd(&posA[cA], 1);
        if (pA < CAP) {
            int2 o;
            o.x = s | ((d & (CH - 1)) << 17);
            o.y = __float_as_int(wf);
            stA[(size_t)cA * CAP + pA] = o;
        }
        int cB = s >> CHS;
        int pB = baseB[cB] + atomicAdd(&posB[cB], 1);
        if (pB < CAP) {
            stB[(size_t)cB * CAP + pB] =
                ((unsigned)(s & (CH - 1)) << 16) | (unsigned)f2bf(wf);
        }
    }
}

// ---------------- per-chunk deg segment-sum (packed stB) ----------------
__global__ __launch_bounds__(256) void deg_chunk_kernel(const int* __restrict__ gcB,
                                                        const unsigned* __restrict__ stB,
                                                        float* __restrict__ deg, int n) {
    __shared__ float acc[CH];
    int c = blockIdx.x, kb = blockIdx.y, KB = gridDim.y;
    for (int i = threadIdx.x; i < CH; i += 256) acc[i] = 0.f;
    __syncthreads();
    int m = min(gcB[c], CAP);
    int per = (m + KB - 1) / KB;
    int i0 = kb * per, i1 = min(m, i0 + per);
    size_t base = (size_t)c * CAP;
    for (int i = i0 + threadIdx.x; i < i1; i += 256) {
        unsigned v = stB[base + i];
        atomicAdd(&acc[v >> 16], bf2f((ushort_t)(v & 0xFFFFu)));
    }
    __syncthreads();
    int nb = c * CH, lim = min(CH, n - nb);
    for (int i = threadIdx.x; i < lim; i += 256) {
        float v = acc[i];
        if (v != 0.f) atomicAdd(&deg[nb + i], v);
    }
}

__global__ void dinv_kernel(float* __restrict__ deg, int n) {
    int i = blockIdx.x * blockDim.x + threadIdx.x;
    if (i >= n) return;
    float d = deg[i];
    deg[i] = (d > 0.f) ? rsqrtf(d) : 0.f;
}

// ---------------- chunk-base scan (1 block, 512 threads, nch <= 512) ----------------
__global__ __launch_bounds__(512) void cbase_kernel(const int* __restrict__ gcA,
                                                    int* __restrict__ cbase,
                                                    int* __restrict__ rp, int nch, int n) {
    __shared__ int sd[MAXCH];
    int t = threadIdx.x;
    sd[t] = (t < nch) ? min(gcA[t], CAP) : 0;
    __syncthreads();
    for (int off = 1; off < MAXCH; off <<= 1) {
        int y = (t >= off) ? sd[t - off] : 0;
        __syncthreads();
        sd[t] += y;
        __syncthreads();
    }
    if (t < nch) cbase[t] = (t > 0) ? sd[t - 1] : 0;
    if (t == 0) rp[n] = sd[nch - 1];
}

// ---------------- per-chunk CSR build: count -> scan -> rp -> single-pass scatter ----------------
__global__ __launch_bounds__(256) void csr_chunk_kernel(const int* __restrict__ gcA,
                                                        const int* __restrict__ cbase,
                                                        const int2* __restrict__ stA,
                                                        const float* __restrict__ dinv,
                                                        int* __restrict__ rp,
                                                        int2* __restrict__ cv, int n) {
    __shared__ int lcnt[CH];
    __shared__ int lrp[CH];
    __shared__ float ldinv[CH];
    __shared__ int sdata[256];
    int c = blockIdx.x;
    int nb = c * CH, lim = min(CH, n - nb);
    int m = min(gcA[c], CAP);
    size_t sb = (size_t)c * CAP;
    int t = threadIdx.x;
    if (t < CH) lcnt[t] = 0;
    if (t < lim) ldinv[t] = dinv[nb + t];
    __syncthreads();
    for (int i = t; i < m; i += 256) atomicAdd(&lcnt[stA[sb + i].x >> 17], 1);
    __syncthreads();
    int v = (t < CH) ? lcnt[t] : 0;
    sdata[t] = v;
    __syncthreads();
    for (int off = 1; off < 256; off <<= 1) {
        int y = (t >= off) ? sdata[t - off] : 0;
        __syncthreads();
        sdata[t] += y;
        __syncthreads();
    }
    if (t < CH) lrp[t] = sdata[t] - v;
    __syncthreads();
    int base = cbase[c];
    if (t < lim) rp[nb + t] = base + lrp[t];
    if (t < CH) lcnt[t] = 0;
    __syncthreads();
    for (int i = t; i < m; i += 256) {
        int2 sv = stA[sb + i];
        int sN = sv.x & 0x1FFFF;
        int dl = sv.x >> 17;
        float nv = dinv[sN] * __int_as_float(sv.y) * ldinv[dl];
        int o = base + lrp[dl] + atomicAdd(&lcnt[dl], 1);
        int2 oo;
        oo.x = sN;
        oo.y = __float_as_int(nv);
        cv[o] = oo;
    }
}

// ---------------- merged W transpose + bf16 for all 3 layers ----------------
__global__ void wt_all_kernel(const float* __restrict__ W1, const float* __restrict__ W2,
                              const float* __restrict__ W3, ushort_t* __restrict__ Wt1,
                              ushort_t* __restrict__ Wt2, ushort_t* __restrict__ Wt3) {
    int i = blockIdx.x * blockDim.x + threadIdx.x;
    if (i < 24576) {
        int m = i / 8192, rem = i % 8192, f = rem / 64, g = rem % 64;
        Wt1[((size_t)(m * 64 + g)) * 128 + f] = f2bf(W1[i]);
    } else if (i < 24576 + 6144) {
        int j = i - 24576;
        int m = j / 2048, rem = j % 2048, f = rem / 32, g = rem % 32;
        Wt2[((size_t)(m * 32 + g)) * 64 + f] = f2bf(W2[j]);
    } else if (i < 24576 + 6144 + 1536) {
        int j = i - 24576 - 6144;
        int m = j / 512, rem = j % 512, f = rem / 16, g = rem % 16;
        Wt3[((size_t)(m * 16 + g)) * 32 + f] = f2bf(W3[j]);
    }
}

// ---------------- MFMA GEMM: 32 rows/wave (two A-frags share each B-frag) ----------------
template <int F, int G, bool A_BF16>
__global__ __launch_bounds__(256) void gemm_mfma(const void* __restrict__ Hv,
                                                 const ushort_t* __restrict__ Wt,
                                                 ushort_t* __restrict__ YA16,
                                                 ushort_t* __restrict__ YB16,
                                                 ushort_t* __restrict__ C16, int n) {
    constexpr int CT = G / 16;
    const int tid = threadIdx.x;
    const int wave = tid >> 6;
    const int lane = tid & 63;
    const int l16 = lane & 15;
    const int lk8 = (lane >> 4) * 8;

    const int rowBase = blockIdx.x * 128 + wave * 32;
    int rA0 = rowBase + l16;
    int rA1 = rowBase + 16 + l16;
    if (rA0 >= n) rA0 = n - 1;
    if (rA1 >= n) rA1 = n - 1;

    f32x4 acc[2][3][CT];
#pragma unroll
    for (int h = 0; h < 2; ++h)
#pragma unroll
        for (int m = 0; m < 3; ++m)
#pragma unroll
            for (int ct = 0; ct < CT; ++ct)
#pragma unroll
                for (int j = 0; j < 4; ++j) acc[h][m][ct][j] = 0.f;

#pragma unroll
    for (int ks = 0; ks < F; ks += 32) {
        short8 a0, a1;
        if constexpr (A_BF16) {
            a0 = *(const short8*)((const ushort_t*)Hv + (size_t)rA0 * F + ks + lk8);
            a1 = *(const short8*)((const ushort_t*)Hv + (size_t)rA1 * F + ks + lk8);
        } else {
            const float* ap0 = (const float*)Hv + (size_t)rA0 * F + ks + lk8;
            const float* ap1 = (const float*)Hv + (size_t)rA1 * F + ks + lk8;
            float4 f00 = *(const float4*)ap0;
            float4 f01 = *(const float4*)(ap0 + 4);
            float4 f10 = *(const float4*)ap1;
            float4 f11 = *(const float4*)(ap1 + 4);
            a0[0] = (short)f2bf(f00.x); a0[1] = (short)f2bf(f00.y);
            a0[2] = (short)f2bf(f00.z); a0[3] = (short)f2bf(f00.w);
            a0[4] = (short)f2bf(f01.x); a0[5] = (short)f2bf(f01.y);
            a0[6] = (short)f2bf(f01.z); a0[7] = (short)f2bf(f01.w);
            a1[0] = (short)f2bf(f10.x); a1[1] = (short)f2bf(f10.y);
            a1[2] = (short)f2bf(f10.z); a1[3] = (short)f2bf(f10.w);
            a1[4] = (short)f2bf(f11.x); a1[5] = (short)f2bf(f11.y);
            a1[6] = (short)f2bf(f11.z); a1[7] = (short)f2bf(f11.w);
        }
#pragma unroll
        for (int m = 0; m < 3; ++m) {
#pragma unroll
            for (int ct = 0; ct < CT; ++ct) {
                short8 b = *(const short8*)(Wt + ((size_t)(m * G + ct * 16 + l16)) * F +
                                            ks + lk8);
                acc[0][m][ct] = __builtin_amdgcn_mfma_f32_16x16x32_bf16(a0, b, acc[0][m][ct], 0, 0, 0);
                acc[1][m][ct] = __builtin_amdgcn_mfma_f32_16x16x32_bf16(a1, b, acc[1][m][ct], 0, 0, 0);
            }
        }
    }

#pragma unroll
    for (int h = 0; h < 2; ++h) {
        const int r0 = rowBase + h * 16 + (lane >> 4) * 4;
#pragma unroll
        for (int ct = 0; ct < CT; ++ct) {
            const int col = ct * 16 + l16;
#pragma unroll
            for (int j = 0; j < 4; ++j) {
                int r = r0 + j;
                if (r < n) {
                    size_t idx = (size_t)r * G + col;
                    YA16[idx] = f2bf(acc[h][0][ct][j] - acc[h][2][ct][j]);
                    YB16[idx] = f2bf(acc[h][1][ct][j]);
                    C16[idx] = f2bf(acc[h][2][ct][j]);
                }
            }
        }
    }
}

// ---------------- row-major bf16 SpMM, 8-deep gather pipeline ----------------
template <int G, int MODE>
__global__ __launch_bounds__(256) void spmm_bf16(const ushort_t* __restrict__ Hg,
                                                 const ushort_t* __restrict__ Yres,
                                                 const float* __restrict__ bias,
                                                 ushort_t* __restrict__ outS,
                                                 const int2* __restrict__ cv,
                                                 const int* __restrict__ rp, int n) {
    constexpr int TPR = G / 4;
    constexpr int RPB = 256 / TPR;
    int row = blockIdx.x * RPB + threadIdx.x / TPR;
    if (row >= n) return;
    int g = (threadIdx.x % TPR) * 4;
    float a0 = 0.f, a1 = 0.f, a2 = 0.f, a3 = 0.f;
    int e = rp[row], e1 = rp[row + 1];
    for (; e + 8 <= e1; e += 8) {
        int2 c[8];
        ushort4 h[8];
#pragma unroll
        for (int k = 0; k < 8; ++k) c[k] = cv[e + k];
#pragma unroll
        for (int k = 0; k < 8; ++k) h[k] = *(const ushort4*)(Hg + (size_t)c[k].x * G + g);
#pragma unroll
        for (int k = 0; k < 8; ++k) {
            float v = __int_as_float(c[k].y);
            a0 = fmaf(v, bf2f(h[k].x), a0);
            a1 = fmaf(v, bf2f(h[k].y), a1);
            a2 = fmaf(v, bf2f(h[k].z), a2);
            a3 = fmaf(v, bf2f(h[k].w), a3);
        }
    }
    for (; e + 4 <= e1; e += 4) {
        int2 c[4];
        ushort4 h[4];
#pragma unroll
        for (int k = 0; k < 4; ++k) c[k] = cv[e + k];
#pragma unroll
        for (int k = 0; k < 4; ++k) h[k] = *(const ushort4*)(Hg + (size_t)c[k].x * G + g);
#pragma unroll
        for (int k = 0; k < 4; ++k) {
            float v = __int_as_float(c[k].y);
            a0 = fmaf(v, bf2f(h[k].x), a0);
            a1 = fmaf(v, bf2f(h[k].y), a1);
            a2 = fmaf(v, bf2f(h[k].z), a2);
            a3 = fmaf(v, bf2f(h[k].w), a3);
        }
    }
    for (; e < e1; ++e) {
        int2 c = cv[e];
        float v = __int_as_float(c.y);
        ushort4 hv = *(const ushort4*)(Hg + (size_t)c.x * G + g);
        a0 = fmaf(v, bf2f(hv.x), a0);
        a1 = fmaf(v, bf2f(hv.y), a1);
        a2 = fmaf(v, bf2f(hv.z), a2);
        a3 = fmaf(v, bf2f(hv.w), a3);
    }
    size_t idx = (size_t)row * G + g;
    ushort4 yv = *(const ushort4*)(Yres + idx);
    ushort4 o;
    if (MODE == 1) {
        o.x = f2bf(bf2f(yv.x) - 2.f * a0);
        o.y = f2bf(bf2f(yv.y) - 2.f * a1);
        o.z = f2bf(bf2f(yv.z) - 2.f * a2);
        o.w = f2bf(bf2f(yv.w) - 2.f * a3);
    } else {
        float4 bv = *(const float4*)(bias + g);
        o.x = f2bf(fmaxf(bf2f(yv.x) - a0 + bv.x, 0.f));
        o.y = f2bf(fmaxf(bf2f(yv.y) - a1 + bv.y, 0.f));
        o.z = f2bf(fmaxf(bf2f(yv.z) - a2 + bv.z, 0.f));
        o.w = f2bf(fmaxf(bf2f(yv.w) - a3 + bv.w, 0.f));
    }
    *(ushort4*)(outS + idx) = o;
}

// ---------------- layer 4 (fp32 tables; bf16 H3 input) ----------------

__global__ void gemm4(const ushort_t* __restrict__ H, const float* __restrict__ W,
                      float* __restrict__ YA, float* __restrict__ YB, float* __restrict__ C,
                      int n) {
    __shared__ float Ws[3 * 16 * 4];
    if (threadIdx.x < 192) Ws[threadIdx.x] = W[threadIdx.x];
    __syncthreads();
    int i = blockIdx.x * blockDim.x + threadIdx.x;
    if (i >= n) return;
    const ushort_t* h = H + (size_t)i * 16;
    float a[4], b[4], c[4];
#pragma unroll
    for (int g = 0; g < 4; ++g) a[g] = b[g] = c[g] = 0.f;
#pragma unroll
    for (int j = 0; j < 2; ++j) {
        short8 hv = *(const short8*)(h + j * 8);
#pragma unroll
        for (int k = 0; k < 8; ++k) {
            int f = j * 8 + k;
            float hf = bf2f((ushort_t)hv[k]);
#pragma unroll
            for (int g = 0; g < 4; ++g) {
                a[g] = fmaf(hf, Ws[f * 4 + g], a[g]);
                b[g] = fmaf(hf, Ws[64 + f * 4 + g], b[g]);
                c[g] = fmaf(hf, Ws[128 + f * 4 + g], c[g]);
            }
        }
    }
    float4 oa, ob, oc;
    oa.x = a[0] - c[0]; oa.y = a[1] - c[1]; oa.z = a[2] - c[2]; oa.w = a[3] - c[3];
    ob.x = b[0]; ob.y = b[1]; ob.z = b[2]; ob.w = b[3];
    oc.x = c[0]; oc.y = c[1]; oc.z = c[2]; oc.w = c[3];
    *(float4*)(YA + (size_t)i * 4) = oa;
    *(float4*)(YB + (size_t)i * 4) = ob;
    *(float4*)(C + (size_t)i * 4) = oc;
}

__global__ void spmm4(const float* __restrict__ C, const float* __restrict__ YB,
                      float* __restrict__ S, const int2* __restrict__ cv,
                      const int* __restrict__ rp, int n) {
    int row = blockIdx.x * blockDim.x + threadIdx.x;
    if (row >= n) return;
    float a0 = 0.f, a1 = 0.f, a2 = 0.f, a3 = 0.f;
    int e1 = rp[row + 1];
    for (int e = rp[row]; e < e1; ++e) {
        int2 c = cv[e];
        float v = __int_as_float(c.y);
        float4 cvv = *(const float4*)(C + (size_t)c.x * 4);
        a0 = fmaf(v, cvv.x, a0);
        a1 = fmaf(v, cvv.y, a1);
        a2 = fmaf(v, cvv.z, a2);
        a3 = fmaf(v, cvv.w, a3);
    }
    float4 yb = *(const float4*)(YB + (size_t)row * 4);
    float4 o;
    o.x = yb.x - 2.f * a0;
    o.y = yb.y - 2.f * a1;
    o.z = yb.z - 2.f * a2;
    o.w = yb.w - 2.f * a3;
    *(float4*)(S + (size_t)row * 4) = o;
}

__global__ void layer4_final(const float* __restrict__ S, const float* __restrict__ YA,
                             const float* __restrict__ b, float* __restrict__ out,
                             const int2* __restrict__ cv, const int* __restrict__ rp, int n) {
    int row = blockIdx.x * blockDim.x + threadIdx.x;
    if (row >= n) return;
    float a0 = 0.f, a1 = 0.f, a2 = 0.f, a3 = 0.f;
    int e1 = rp[row + 1];
    for (int e = rp[row]; e < e1; ++e) {
        int2 c = cv[e];
        float v = __int_as_float(c.y);
        float4 sv = *(const float4*)(S + (size_t)c.x * 4);
        a0 = fmaf(v, sv.x, a0);
        a1 = fmaf(v, sv.y, a1);
        a2 = fmaf(v, sv.z, a2);
        a3 = fmaf(v, sv.w, a3);
    }
    float4 ya = *(const float4*)(YA + (size_t)row * 4);
    float o0 = ya.x - a0 + b[0];
    float o1 = ya.y - a1 + b[1];
    float o2 = ya.z - a2 + b[2];
    float o3 = ya.w - a3 + b[3];
    float m = fmaxf(fmaxf(o0, o1), fmaxf(o2, o3));
    float s = expf(o0 - m) + expf(o1 - m) + expf(o2 - m) + expf(o3 - m);
    float ls = m + logf(s);
    float4 r;
    r.x = o0 - ls;
    r.y = o1 - ls;
    r.z = o2 - ls;
    r.w = o3 - ls;
    *(float4*)(out + (size_t)row * 4) = r;
}

// ---------------- launch ----------------

static inline char* align_up(char* p, size_t a) {
    return (char*)(((uintptr_t)p + a - 1) & ~(uintptr_t)(a - 1));
}

extern "C" void kernel_launch(void* const* d_in, const int* in_sizes, int n_in,
                              void* d_out, int out_size, void* d_ws, size_t ws_size,
                              hipStream_t stream) {
    const float* x = (const float*)d_in[0];
    const int* ei = (const int*)d_in[1];
    const float* ew = (const float*)d_in[2];
    const float* W1 = (const float*)d_in[3];
    const float* b1 = (const float*)d_in[4];
    const float* W2 = (const float*)d_in[5];
    const float* b2 = (const float*)d_in[6];
    const float* W3 = (const float*)d_in[7];
    const float* b3 = (const float*)d_in[8];
    const float* W4 = (const float*)d_in[9];
    const float* b4 = (const float*)d_in[10];
    float* out = (float*)d_out;

    const int n = in_sizes[0] / D_IN;  // 100000
    const int E = in_sizes[2];         // 1600000
    const int* src = ei;
    const int* dst = ei + E;
    const int nch = (n + CH - 1) / CH;  // 391

    char* p = (char*)d_ws;
    int2* cv = (int2*)p;          p += (size_t)E * 8;
    float* deg = (float*)p;       p += (size_t)n * 4;
    int* rp = (int*)p;            p = align_up(p + (size_t)(n + 1) * 4, 64);
    int* gcA = (int*)p;           p += MAXCH * 4;
    int* gcB = (int*)p;           p += MAXCH * 4;
    int* cbase = (int*)p;         p = align_up(p + MAXCH * 4, 64);
    ushort_t* Wt1 = (ushort_t*)p; p = align_up(p + (size_t)192 * 128 * 2, 64);
    ushort_t* Wt2 = (ushort_t*)p; p = align_up(p + (size_t)96 * 64 * 2, 64);
    ushort_t* Wt3 = (ushort_t*)p; p = align_up(p + (size_t)48 * 32 * 2, 64);
    // big region: staging (dead after CSR build) overlaid with YA16/YB16/C16/S16
    char* big = p;
    ushort_t* YA16 = (ushort_t*)big;
    ushort_t* YB16 = (ushort_t*)(big + (size_t)n * 64 * 2);
    ushort_t* C16 = (ushort_t*)(big + (size_t)n * 64 * 2 * 2);
    ushort_t* S16 = (ushort_t*)(big + (size_t)n * 64 * 2 * 3);
    int2* stA = (int2*)big;                                    // nch*CAP*8 = 19.2MB
    unsigned* stB = (unsigned*)(big + (size_t)nch * CAP * 8);  // nch*CAP*4 = 9.6MB
    p = align_up(big + (size_t)n * 64 * 2 * 4, 64);
    ushort_t* H1 = (ushort_t*)p;  p = align_up(p + (size_t)n * 64 * 2, 64);
    ushort_t* H2 = (ushort_t*)p;  p = align_up(p + (size_t)n * 32 * 2, 64);
    ushort_t* H3 = (ushort_t*)p;  p = align_up(p + (size_t)n * 16 * 2, 64);
    float* YA4 = (float*)p;       p = align_up(p + (size_t)n * 4 * 4, 64);
    float* YB4 = (float*)p;       p = align_up(p + (size_t)n * 4 * 4, 64);
    float* C4 = (float*)p;        p = align_up(p + (size_t)n * 4 * 4, 64);
    float* S4 = (float*)p;        p = align_up(p + (size_t)n * 4 * 4, 64);

    const int TB = 256;
    int nb256 = (n + TB - 1) / TB;
    int gm = (n + 127) / 128;

    // ---- preprocessing ----
    hipMemsetAsync(deg, 0, (size_t)n * 4, stream);
    hipMemsetAsync(gcA, 0, MAXCH * 4 * 2, stream);
    bin2_kernel<<<NBIN, 1024, 0, stream>>>(src, dst, ew, gcA, gcB, stA, stB, E, nch);
    {
        dim3 dg(nch, 4);
        deg_chunk_kernel<<<dg, 256, 0, stream>>>(gcB, stB, deg, n);
    }
    dinv_kernel<<<nb256, TB, 0, stream>>>(deg, n);
    cbase_kernel<<<1, MAXCH, 0, stream>>>(gcA, cbase, rp, nch, n);
    csr_chunk_kernel<<<nch, 256, 0, stream>>>(gcA, cbase, stA, deg, rp, cv, n);

    wt_all_kernel<<<(24576 + 6144 + 1536 + 255) / 256, 256, 0, stream>>>(W1, W2, W3, Wt1,
                                                                         Wt2, Wt3);

    // ---- layer 1: F=128, G=64 ----
    {
        constexpr int G = 64;
        gemm_mfma<128, G, false><<<gm, 256, 0, stream>>>(x, Wt1, YA16, YB16, C16, n);
        int sb = (n + (1024 / G) - 1) / (1024 / G);
        spmm_bf16<G, 1><<<sb, 256, 0, stream>>>(C16, YB16, nullptr, S16, cv, rp, n);
        spmm_bf16<G, 2><<<sb, 256, 0, stream>>>(S16, YA16, b1, H1, cv, rp, n);
    }
    // ---- layer 2: F=64, G=32 ----
    {
        constexpr int G = 32;
        gemm_mfma<64, G, true><<<gm, 256, 0, stream>>>(H1, Wt2, YA16, YB16, C16, n);
        int sb = (n + (1024 / G) - 1) / (1024 / G);
        spmm_bf16<G, 1><<<sb, 256, 0, stream>>>(C16, YB16, nullptr, S16, cv, rp, n);
        spmm_bf16<G, 2><<<sb, 256, 0, stream>>>(S16, YA16, b2, H2, cv, rp, n);
    }
    // ---- layer 3: F=32, G=16 ----
    {
        constexpr int G = 16;
        gemm_mfma<32, G, true><<<gm, 256, 0, stream>>>(H2, Wt3, YA16, YB16, C16, n);
        int sb = (n + (1024 / G) - 1) / (1024 / G);
        spmm_bf16<G, 1><<<sb, 256, 0, stream>>>(C16, YB16, nullptr, S16, cv, rp, n);
        spmm_bf16<G, 2><<<sb, 256, 0, stream>>>(S16, YA16, b3, H3, cv, rp, n);
    }
    // ---- layer 4: F=16, G=4 (fp32 tables) ----
    {
        gemm4<<<nb256, 256, 0, stream>>>(H3, W4, YA4, YB4, C4, n);
        spmm4<<<nb256, 256, 0, stream>>>(C4, YB4, S4, cv, rp, n);
        layer4_final<<<nb256, 256, 0, stream>>>(S4, YA4, b4, out, cv, rp, n);
    }
}